// Round 3
// baseline (1204.883 us; speedup 1.0000x reference)
//
#include <hip/hip_runtime.h>

typedef unsigned short ushort_t;
typedef __attribute__((ext_vector_type(8))) __bf16 bf16x8;
typedef __attribute__((ext_vector_type(8))) unsigned short ushort8;
typedef __attribute__((ext_vector_type(4))) float floatx4;
typedef __attribute__((ext_vector_type(16))) float floatx16;

#define VN 778
#define KNB 9

__device__ __forceinline__ float bf2f(unsigned short s) {
  union { unsigned int u; float f; } x; x.u = ((unsigned int)s) << 16; return x.f;
}
__device__ __forceinline__ unsigned short f2bf(float f) {
  union { float f; unsigned int u; } x; x.f = f;
  unsigned int r = x.u + 0x7fffu + ((x.u >> 16) & 1u);
  return (unsigned short)(r >> 16);
}

// ---------------- prologue: occ probabilities, finger ids, wh transpose ----
__global__ void prep_misc(const float* __restrict__ pred_occ,
                          const int* f0, const int* f1, const int* f2,
                          const int* f3, const int* f4,
                          int n0, int n1, int n2, int n3, int n4,
                          const float* __restrict__ wh,
                          float* __restrict__ occ, int* __restrict__ fid,
                          float* __restrict__ whT) {
  int t = threadIdx.x;
  for (int i = t; i < 192 * 5; i += 256) {
    int r = i / 5, f = i % 5;
    float p0 = pred_occ[r * 10 + f];
    float p1 = pred_occ[r * 10 + 5 + f];
    occ[i] = 1.0f / (1.0f + __expf(p1 - p0));  // softmax over 2 classes, class 0
  }
  for (int i = t; i < VN; i += 256) fid[i] = -1;
  __syncthreads();
  const int* fp[5] = {f0, f1, f2, f3, f4};
  int fn[5] = {n0, n1, n2, n3, n4};
  for (int fi = 0; fi < 5; ++fi) {  // sequential: later fingers overwrite
    for (int i = t; i < fn[fi]; i += 256) fid[fp[fi][i]] = fi;
    __syncthreads();
  }
  for (int i = t; i < 3 * 2304; i += 256) {
    int o = i / 2304, k = i % 2304;
    whT[i] = wh[k * 3 + o];
  }
}

// ---------------- weighted view mix: wx[b,v,c] = sum_j softmax(w)_j x_j ----
// x is f32 [192,V,256]; output wx is bf16 [64,V,256].
__global__ void wx_kernel(const float* __restrict__ x, const float* __restrict__ occ,
                          const int* __restrict__ fid, ushort_t* __restrict__ wx) {
  int g = blockIdx.x * 256 + threadIdx.x;  // 8-ch chunk id over 64*778*32 (exact)
  int c8 = (g & 31) << 3;
  int bv = g >> 5;
  int b = bv / VN;
  int v = bv - b * VN;
  int f = fid[v];
  float w0 = 1.f, w1 = 1.f, w2 = 1.f;
  if (f >= 0) {
    w0 = occ[b * 5 + f];
    w1 = occ[(64 + b) * 5 + f];
    w2 = occ[(128 + b) * 5 + f];
  }
  float m = fmaxf(w0, fmaxf(w1, w2));
  float e0 = __expf(w0 - m), e1 = __expf(w1 - m), e2 = __expf(w2 - m);
  float inv = 1.0f / (e0 + e1 + e2);
  e0 *= inv; e1 *= inv; e2 *= inv;
  size_t base = (size_t)bv * 256 + c8;
  const size_t V1 = (size_t)64 * VN * 256, V2 = (size_t)128 * VN * 256;
  floatx4 x0a = *(const floatx4*)(x + base);
  floatx4 x0b = *(const floatx4*)(x + base + 4);
  floatx4 x1a = *(const floatx4*)(x + V1 + base);
  floatx4 x1b = *(const floatx4*)(x + V1 + base + 4);
  floatx4 x2a = *(const floatx4*)(x + V2 + base);
  floatx4 x2b = *(const floatx4*)(x + V2 + base + 4);
  ushort8 o;
#pragma unroll
  for (int e = 0; e < 4; ++e) {
    o[e]     = f2bf(e0 * x0a[e] + e1 * x1a[e] + e2 * x2a[e]);
    o[e + 4] = f2bf(e0 * x0b[e] + e1 * x1b[e] + e2 * x2b[e]);
  }
  *(ushort8*)(wx + base) = o;
}

// ---------------- pack W[k][n] (f32) into bf16 MFMA B-fragment order --------
// chunk = ((n/32)*(Ktot/16) + k/16)*64 + ((k%16)/8)*32 + (n%32); 8 bf16 (k-contig)
__global__ void pack_w(const float* __restrict__ w, ushort_t* __restrict__ wP,
                       int N, int ksn, int total) {
  int chunk = blockIdx.x * 256 + threadIdx.x;
  if (chunk >= total) return;
  int lane = chunk & 63;
  int rest = chunk >> 6;
  int ks = rest % ksn;
  int tn = rest / ksn;
  int n = (tn << 5) + (lane & 31);
  int kb = (ks << 4) + ((lane >> 5) << 3);
  ushort8 o;
#pragma unroll
  for (int j = 0; j < 8; ++j) o[j] = f2bf(w[(size_t)(kb + j) * N + n]);
  *(ushort8*)(wP + (size_t)chunk * 8) = o;
}

// ---------------- spiral gathered GEMM -------------------------------------
// block = one vertex v, 4 waves; wave tile 64(b) x 64(n); 32x32x16 bf16 MFMA.
// A staged per neighbor: global loads -> regs -> ds_write_b128, XOR swizzle on
// the LDS-destination side. SPLIT: channels [0,256) from bf16 act0 (wx),
// [256,512) from f32 actF (x view 0), converted during staging.
template <int CIN, bool SPLIT>
__global__ __launch_bounds__(256, 2) void spiral_gemm(
    const ushort_t* __restrict__ act0, const float* __restrict__ actF,
    const ushort_t* __restrict__ wP, const float* __restrict__ bias,
    const int* __restrict__ idx, ushort_t* __restrict__ out, int NOUT) {
  constexpr int CW = CIN / 8;                  // 8-ch (16B bf16) chunks per row
  constexpr int LOGCW = (CIN == 512) ? 6 : 5;
  constexpr int KSN = CIN / 16;                // MFMA K-steps per neighbor
  const int KtotSteps = KNB * KSN;
  __shared__ __align__(16) ushort_t Alds[64 * CIN];  // 64KB (CIN=512) / 32KB (256)
  const int v = blockIdx.x;
  const int n0 = blockIdx.y << 8;
  const int tid = threadIdx.x;
  const int lane = tid & 63;
  const int wv = tid >> 6;
  const int mlo = lane & 31;
  const int q = lane >> 5;
  const int xm = mlo & 7;
  floatx16 acc00{}, acc01{}, acc10{}, acc11{};
  const int tn0 = (n0 >> 5) + (wv << 1);
  const ushort_t* bp0 = wP + (size_t)tn0 * KtotSteps * 512 + lane * 8;
  const ushort_t* bp1 = bp0 + (size_t)KtotSteps * 512;
  const int* iv = idx + v * KNB;
  const int a_off0 = (mlo * CW) * 8;
  const int a_off1 = ((mlo + 32) * CW) * 8;
  for (int nbr = 0; nbr < KNB; ++nbr) {
    const int nv = iv[nbr];
    __syncthreads();  // previous-iter readers done before restaging
#pragma unroll
    for (int it = 0; it < (64 * CW) / 256; ++it) {
      int L = it * 256 + tid;      // source chunk id: row b, chunk jj
      int b = L >> LOGCW;
      int jj = L & (CW - 1);
      int c = jj << 3;
      ushort8 val;
      if (SPLIT && c >= 256) {
        const float* src = actF + ((size_t)(b * VN + nv)) * 256 + (c - 256);
        floatx4 fa = *(const floatx4*)src;
        floatx4 fb = *(const floatx4*)(src + 4);
#pragma unroll
        for (int e = 0; e < 4; ++e) { val[e] = f2bf(fa[e]); val[e + 4] = f2bf(fb[e]); }
      } else {
        const ushort_t* src = act0 + ((size_t)(b * VN + nv)) * (SPLIT ? 256 : CIN) + c;
        val = *(const ushort8*)src;
      }
      int slot = jj ^ (b & 7);     // swizzle on LDS-destination side
      *(ushort8*)&Alds[(size_t)(b * CW + slot) * 8] = val;
    }
    __syncthreads();
#pragma unroll 4
    for (int ks = 0; ks < KSN; ++ks) {
      int jj0 = ((ks << 1) + q) ^ xm;
      bf16x8 a0 = *(const bf16x8*)&Alds[a_off0 + jj0 * 8];
      bf16x8 a1 = *(const bf16x8*)&Alds[a_off1 + jj0 * 8];
      bf16x8 b0 = *(const bf16x8*)bp0; bp0 += 512;
      bf16x8 b1 = *(const bf16x8*)bp1; bp1 += 512;
      acc00 = __builtin_amdgcn_mfma_f32_32x32x16_bf16(a0, b0, acc00, 0, 0, 0);
      acc10 = __builtin_amdgcn_mfma_f32_32x32x16_bf16(a1, b0, acc10, 0, 0, 0);
      acc01 = __builtin_amdgcn_mfma_f32_32x32x16_bf16(a0, b1, acc01, 0, 0, 0);
      acc11 = __builtin_amdgcn_mfma_f32_32x32x16_bf16(a1, b1, acc11, 0, 0, 0);
    }
  }
  // epilogue: C/D layout col=lane&31, row=(reg&3)+8*(reg>>2)+4*(lane>>5)
  const int na = n0 + (wv << 6) + mlo;
  const int nb = na + 32;
  const float ba = bias[na];
  const float bb = bias[nb];
#pragma unroll
  for (int r = 0; r < 16; ++r) {
    int m = (r & 3) + ((r >> 2) << 3) + (q << 2);
    size_t o0 = ((size_t)(m * VN + v)) * NOUT;
    size_t o1 = ((size_t)((m + 32) * VN + v)) * NOUT;
    float v00 = acc00[r] + ba; v00 = v00 > 0.f ? v00 : 0.f;
    float v01 = acc01[r] + bb; v01 = v01 > 0.f ? v01 : 0.f;
    float v10 = acc10[r] + ba; v10 = v10 > 0.f ? v10 : 0.f;
    float v11 = acc11[r] + bb; v11 = v11 > 0.f ? v11 : 0.f;
    out[o0 + na] = f2bf(v00);
    out[o0 + nb] = f2bf(v01);
    out[o1 + na] = f2bf(v10);
    out[o1 + nb] = f2bf(v11);
  }
}

// ---------------- head: gathered [64 x 2304] @ [2304 x 3], f32 out ---------
__global__ void head_kernel(const ushort_t* __restrict__ act, const float* __restrict__ whT,
                            const float* __restrict__ bh, const int* __restrict__ idx,
                            float* __restrict__ out) {
  __shared__ __align__(16) ushort_t Alds[64 * 256];
  const int v = blockIdx.x;
  const int tid = threadIdx.x;
  float a0 = 0.f, a1 = 0.f, a2 = 0.f;
  const int b = tid;  // valid when tid < 64
  const int xm = b & 7;
  for (int nbr = 0; nbr < KNB; ++nbr) {
    const int nv = idx[v * KNB + nbr];
    __syncthreads();
#pragma unroll
    for (int it = 0; it < 8; ++it) {
      int L = it * 256 + tid;
      int bb = L >> 5;
      int jj = L & 31;
      ushort8 val = *(const ushort8*)(act + ((size_t)(bb * VN + nv)) * 256 + (jj << 3));
      int slot = jj ^ (bb & 7);
      *(ushort8*)&Alds[(size_t)(bb * 32 + slot) * 8] = val;
    }
    __syncthreads();
    if (tid < 64) {
      const float* wp = whT + nbr * 256;
#pragma unroll 4
      for (int j = 0; j < 32; ++j) {
        int jj = j ^ xm;
        ushort8 a8 = *(const ushort8*)&Alds[(b * 32 + jj) * 8];
#pragma unroll
        for (int e = 0; e < 8; ++e) {
          float av = bf2f(a8[e]);
          int k = (j << 3) + e;
          a0 += av * wp[k];
          a1 += av * wp[2304 + k];
          a2 += av * wp[4608 + k];
        }
      }
    }
  }
  if (tid < 64) {
    size_t o = ((size_t)(b * VN + v)) * 3;
    out[o + 0] = a0 + bh[0];
    out[o + 1] = a1 + bh[1];
    out[o + 2] = a2 + bh[2];
  }
}

extern "C" void kernel_launch(void* const* d_in, const int* in_sizes, int n_in,
                              void* d_out, int out_size, void* d_ws, size_t ws_size,
                              hipStream_t stream) {
  const float* x        = (const float*)d_in[0];
  const float* pred_occ = (const float*)d_in[1];
  const int* indices    = (const int*)d_in[2];
  const int* f0 = (const int*)d_in[3];
  const int* f1 = (const int*)d_in[4];
  const int* f2 = (const int*)d_in[5];
  const int* f3 = (const int*)d_in[6];
  const int* f4 = (const int*)d_in[7];
  const float* w0 = (const float*)d_in[8];
  const float* b0 = (const float*)d_in[9];
  const float* w1 = (const float*)d_in[10];
  const float* b1 = (const float*)d_in[11];
  const float* w2 = (const float*)d_in[12];
  const float* b2 = (const float*)d_in[13];
  const float* wh = (const float*)d_in[14];
  const float* bh = (const float*)d_in[15];
  float* outp = (float*)d_out;

  char* ws = (char*)d_ws;
  // ws layout (16B+ aligned): packed bf16 weights, small tables, activation bufs
  ushort_t* wP0 = (ushort_t*)(ws + 0);         // 512 x 4608 bf16 (4,718,592 B)
  ushort_t* wP1 = (ushort_t*)(ws + 4718592);   // 256 x 4608 bf16 (2,359,296 B)
  ushort_t* wP2 = (ushort_t*)(ws + 7077888);   // 256 x 2304 bf16 (1,179,648 B)
  float* whT    = (float*)(ws + 8257536);      // 3 x 2304 f32
  float* occ    = (float*)(ws + 8285184);      // 192 x 5 f32
  int* fid      = (int*)(ws + 8289024);        // 778 i32
  ushort_t* R0  = (ushort_t*)(ws + 8292352);   // wx, later h2   [64,V,256] bf16 25.5MB
  ushort_t* R1  = (ushort_t*)(ws + 33785856);  // h1, later h3   [64,V,512] bf16 51MB
  // total ws use: ~84.8 MB

  prep_misc<<<1, 256, 0, stream>>>(pred_occ, f0, f1, f2, f3, f4,
                                   in_sizes[3], in_sizes[4], in_sizes[5],
                                   in_sizes[6], in_sizes[7], wh, occ, fid, whT);
  pack_w<<<294912 / 256, 256, 0, stream>>>(w0, wP0, 512, 288, 294912);
  pack_w<<<147456 / 256, 256, 0, stream>>>(w1, wP1, 256, 288, 147456);
  pack_w<<<73728 / 256, 256, 0, stream>>>(w2, wP2, 256, 144, 73728);
  wx_kernel<<<6224, 256, 0, stream>>>(x, occ, fid, R0);

  dim3 g0(VN, 2), g1(VN, 1);
  // conv0: in [wx(bf16) | x_view0(f32)] (512ch) -> h1 (512ch bf16)
  spiral_gemm<512, true><<<g0, 256, 0, stream>>>(R0, x, wP0, b0, indices, R1, 512);
  // conv1: h1 (512ch) -> h2 (256ch)
  spiral_gemm<512, false><<<g1, 256, 0, stream>>>(R1, nullptr, wP1, b1, indices, R0, 256);
  // conv2: h2 (256ch) -> h3 (256ch)
  spiral_gemm<256, false><<<g1, 256, 0, stream>>>(R0, nullptr, wP2, b2, indices, R1, 256);
  // head: h3 -> out [64,V,3] f32
  head_kernel<<<VN, 256, 0, stream>>>(R1, whT, bh, indices, outp);
  (void)n_in; (void)out_size; (void)ws_size;
}

// Round 4
// 1018.390 us; speedup vs baseline: 1.1831x; 1.1831x over previous
//
#include <hip/hip_runtime.h>

typedef unsigned short ushort_t;
typedef __attribute__((ext_vector_type(8))) __bf16 bf16x8;
typedef __attribute__((ext_vector_type(8))) unsigned short ushort8;
typedef __attribute__((ext_vector_type(4))) float floatx4;
typedef __attribute__((ext_vector_type(16))) float floatx16;

#define VN 778
#define KNB 9

__device__ __forceinline__ float bf2f(unsigned short s) {
  union { unsigned int u; float f; } x; x.u = ((unsigned int)s) << 16; return x.f;
}
__device__ __forceinline__ unsigned short f2bf(float f) {
  union { float f; unsigned int u; } x; x.f = f;
  unsigned int r = x.u + 0x7fffu + ((x.u >> 16) & 1u);
  return (unsigned short)(r >> 16);
}

// ---------------- prologue: occ probabilities, finger ids, wh transpose ----
__global__ void prep_misc(const float* __restrict__ pred_occ,
                          const int* f0, const int* f1, const int* f2,
                          const int* f3, const int* f4,
                          int n0, int n1, int n2, int n3, int n4,
                          const float* __restrict__ wh,
                          float* __restrict__ occ, int* __restrict__ fid,
                          float* __restrict__ whT) {
  int t = threadIdx.x;
  for (int i = t; i < 192 * 5; i += 256) {
    int r = i / 5, f = i % 5;
    float p0 = pred_occ[r * 10 + f];
    float p1 = pred_occ[r * 10 + 5 + f];
    occ[i] = 1.0f / (1.0f + __expf(p1 - p0));  // softmax over 2 classes, class 0
  }
  for (int i = t; i < VN; i += 256) fid[i] = -1;
  __syncthreads();
  const int* fp[5] = {f0, f1, f2, f3, f4};
  int fn[5] = {n0, n1, n2, n3, n4};
  for (int fi = 0; fi < 5; ++fi) {  // sequential: later fingers overwrite
    for (int i = t; i < fn[fi]; i += 256) fid[fp[fi][i]] = fi;
    __syncthreads();
  }
  for (int i = t; i < 3 * 2304; i += 256) {
    int o = i / 2304, k = i % 2304;
    whT[i] = wh[k * 3 + o];
  }
}

// ---------------- weighted view mix: wx[b,v,c] = sum_j softmax(w)_j x_j ----
// x is f32 [192,V,256]; output wx is bf16 [64,V,256].
__global__ void wx_kernel(const float* __restrict__ x, const float* __restrict__ occ,
                          const int* __restrict__ fid, ushort_t* __restrict__ wx) {
  int g = blockIdx.x * 256 + threadIdx.x;  // 8-ch chunk id over 64*778*32 (exact)
  int c8 = (g & 31) << 3;
  int bv = g >> 5;
  int b = bv / VN;
  int v = bv - b * VN;
  int f = fid[v];
  float w0 = 1.f, w1 = 1.f, w2 = 1.f;
  if (f >= 0) {
    w0 = occ[b * 5 + f];
    w1 = occ[(64 + b) * 5 + f];
    w2 = occ[(128 + b) * 5 + f];
  }
  float m = fmaxf(w0, fmaxf(w1, w2));
  float e0 = __expf(w0 - m), e1 = __expf(w1 - m), e2 = __expf(w2 - m);
  float inv = 1.0f / (e0 + e1 + e2);
  e0 *= inv; e1 *= inv; e2 *= inv;
  size_t base = (size_t)bv * 256 + c8;
  const size_t V1 = (size_t)64 * VN * 256, V2 = (size_t)128 * VN * 256;
  floatx4 x0a = *(const floatx4*)(x + base);
  floatx4 x0b = *(const floatx4*)(x + base + 4);
  floatx4 x1a = *(const floatx4*)(x + V1 + base);
  floatx4 x1b = *(const floatx4*)(x + V1 + base + 4);
  floatx4 x2a = *(const floatx4*)(x + V2 + base);
  floatx4 x2b = *(const floatx4*)(x + V2 + base + 4);
  ushort8 o;
#pragma unroll
  for (int e = 0; e < 4; ++e) {
    o[e]     = f2bf(e0 * x0a[e] + e1 * x1a[e] + e2 * x2a[e]);
    o[e + 4] = f2bf(e0 * x0b[e] + e1 * x1b[e] + e2 * x2b[e]);
  }
  *(ushort8*)(wx + base) = o;
}

// ---------------- pack W[k][n] (f32) into bf16 MFMA B-fragment order --------
// chunk = ((n/32)*(Ktot/16) + k/16)*64 + ((k%16)/8)*32 + (n%32); 8 bf16 (k-contig)
__global__ void pack_w(const float* __restrict__ w, ushort_t* __restrict__ wP,
                       int N, int ksn, int total) {
  int chunk = blockIdx.x * 256 + threadIdx.x;
  if (chunk >= total) return;
  int lane = chunk & 63;
  int rest = chunk >> 6;
  int ks = rest % ksn;
  int tn = rest / ksn;
  int n = (tn << 5) + (lane & 31);
  int kb = (ks << 4) + ((lane >> 5) << 3);
  ushort8 o;
#pragma unroll
  for (int j = 0; j < 8; ++j) o[j] = f2bf(w[(size_t)(kb + j) * N + n]);
  *(ushort8*)(wP + (size_t)chunk * 8) = o;
}

// ---------------- spiral gathered GEMM -------------------------------------
// block = one vertex v, 4 waves; wave tile 64(b) x 64(n); 32x32x16 bf16 MFMA.
// A staged in 256-channel phases (32 KB LDS -> 5 blocks/CU for latency hiding).
// Per phase: barrier, stage 64x256 bf16 (XOR-swizzled 16B chunks on the LDS
// destination), barrier, 16 K-steps. SPLIT: phase h=0 reads bf16 act0 (wx),
// h=1 reads f32 actF (x view 0) converting in-register.
template <int CIN, bool SPLIT>
__global__ __launch_bounds__(256, 4) void spiral_gemm(
    const ushort_t* __restrict__ act0, const float* __restrict__ actF,
    const ushort_t* __restrict__ wP, const float* __restrict__ bias,
    const int* __restrict__ idx, ushort_t* __restrict__ out, int NOUT) {
  constexpr int HALVES = CIN / 256;            // stage phases per neighbor
  __shared__ __align__(16) ushort_t Alds[64 * 256];  // 32 KB
  const int v = blockIdx.x;
  const int n0 = blockIdx.y << 8;
  const int tid = threadIdx.x;
  const int lane = tid & 63;
  const int wv = tid >> 6;
  const int mlo = lane & 31;
  const int q = lane >> 5;
  const int xm = mlo & 7;
  floatx16 acc00{}, acc01{}, acc10{}, acc11{};
  const int KtotSteps = KNB * (CIN / 16);
  const int tn0 = (n0 >> 5) + (wv << 1);
  const ushort_t* bp0 = wP + (size_t)tn0 * KtotSteps * 512 + lane * 8;
  const ushort_t* bp1 = bp0 + (size_t)KtotSteps * 512;
  const int* iv = idx + v * KNB;
  const int a_off0 = (mlo * 32) * 8;           // LDS row stride = 256 ch
  const int a_off1 = ((mlo + 32) * 32) * 8;
  for (int nbr = 0; nbr < KNB; ++nbr) {
    const int nv = iv[nbr];
#pragma unroll
    for (int h = 0; h < HALVES; ++h) {
      __syncthreads();  // previous-phase readers done before restaging
#pragma unroll
      for (int it = 0; it < 8; ++it) {
        int L = it * 256 + tid;    // chunk id: row b, 8-ch chunk jj
        int b = L >> 5;
        int jj = L & 31;
        int c = jj << 3;
        ushort8 val;
        if (SPLIT && h == 1) {
          const float* src = actF + ((size_t)(b * VN + nv)) * 256 + c;
          floatx4 fa = *(const floatx4*)src;
          floatx4 fb = *(const floatx4*)(src + 4);
#pragma unroll
          for (int e = 0; e < 4; ++e) { val[e] = f2bf(fa[e]); val[e + 4] = f2bf(fb[e]); }
        } else {
          const ushort_t* src = act0 + ((size_t)(b * VN + nv)) * (SPLIT ? 256 : CIN)
                                + h * 256 + c;
          val = *(const ushort8*)src;
        }
        int slot = jj ^ (b & 7);   // swizzle on LDS-destination side
        *(ushort8*)&Alds[(size_t)(b * 32 + slot) * 8] = val;
      }
      __syncthreads();
#pragma unroll 4
      for (int ks = 0; ks < 16; ++ks) {
        int jj0 = ((ks << 1) + q) ^ xm;
        bf16x8 a0 = *(const bf16x8*)&Alds[a_off0 + jj0 * 8];
        bf16x8 a1 = *(const bf16x8*)&Alds[a_off1 + jj0 * 8];
        bf16x8 b0v = *(const bf16x8*)bp0; bp0 += 512;
        bf16x8 b1v = *(const bf16x8*)bp1; bp1 += 512;
        acc00 = __builtin_amdgcn_mfma_f32_32x32x16_bf16(a0, b0v, acc00, 0, 0, 0);
        acc10 = __builtin_amdgcn_mfma_f32_32x32x16_bf16(a1, b0v, acc10, 0, 0, 0);
        acc01 = __builtin_amdgcn_mfma_f32_32x32x16_bf16(a0, b1v, acc01, 0, 0, 0);
        acc11 = __builtin_amdgcn_mfma_f32_32x32x16_bf16(a1, b1v, acc11, 0, 0, 0);
      }
    }
  }
  // epilogue: C/D layout col=lane&31, row=(reg&3)+8*(reg>>2)+4*(lane>>5)
  const int na = n0 + (wv << 6) + mlo;
  const int nb = na + 32;
  const float ba = bias[na];
  const float bb = bias[nb];
#pragma unroll
  for (int r = 0; r < 16; ++r) {
    int m = (r & 3) + ((r >> 2) << 3) + (q << 2);
    size_t o0 = ((size_t)(m * VN + v)) * NOUT;
    size_t o1 = ((size_t)((m + 32) * VN + v)) * NOUT;
    float v00 = acc00[r] + ba; v00 = v00 > 0.f ? v00 : 0.f;
    float v01 = acc01[r] + bb; v01 = v01 > 0.f ? v01 : 0.f;
    float v10 = acc10[r] + ba; v10 = v10 > 0.f ? v10 : 0.f;
    float v11 = acc11[r] + bb; v11 = v11 > 0.f ? v11 : 0.f;
    out[o0 + na] = f2bf(v00);
    out[o0 + nb] = f2bf(v01);
    out[o1 + na] = f2bf(v10);
    out[o1 + nb] = f2bf(v11);
  }
}

// ---------------- head: gathered [64 x 2304] @ [2304 x 3], f32 out ---------
__global__ void head_kernel(const ushort_t* __restrict__ act, const float* __restrict__ whT,
                            const float* __restrict__ bh, const int* __restrict__ idx,
                            float* __restrict__ out) {
  __shared__ __align__(16) ushort_t Alds[64 * 256];
  const int v = blockIdx.x;
  const int tid = threadIdx.x;
  float a0 = 0.f, a1 = 0.f, a2 = 0.f;
  const int b = tid;  // valid when tid < 64
  const int xm = b & 7;
  for (int nbr = 0; nbr < KNB; ++nbr) {
    const int nv = idx[v * KNB + nbr];
    __syncthreads();
#pragma unroll
    for (int it = 0; it < 8; ++it) {
      int L = it * 256 + tid;
      int bb = L >> 5;
      int jj = L & 31;
      ushort8 val = *(const ushort8*)(act + ((size_t)(bb * VN + nv)) * 256 + (jj << 3));
      int slot = jj ^ (bb & 7);
      *(ushort8*)&Alds[(size_t)(bb * 32 + slot) * 8] = val;
    }
    __syncthreads();
    if (tid < 64) {
      const float* wp = whT + nbr * 256;
#pragma unroll 4
      for (int j = 0; j < 32; ++j) {
        int jj = j ^ xm;
        ushort8 a8 = *(const ushort8*)&Alds[(b * 32 + jj) * 8];
#pragma unroll
        for (int e = 0; e < 8; ++e) {
          float av = bf2f(a8[e]);
          int k = (j << 3) + e;
          a0 += av * wp[k];
          a1 += av * wp[2304 + k];
          a2 += av * wp[4608 + k];
        }
      }
    }
  }
  if (tid < 64) {
    size_t o = ((size_t)(b * VN + v)) * 3;
    out[o + 0] = a0 + bh[0];
    out[o + 1] = a1 + bh[1];
    out[o + 2] = a2 + bh[2];
  }
}

extern "C" void kernel_launch(void* const* d_in, const int* in_sizes, int n_in,
                              void* d_out, int out_size, void* d_ws, size_t ws_size,
                              hipStream_t stream) {
  const float* x        = (const float*)d_in[0];
  const float* pred_occ = (const float*)d_in[1];
  const int* indices    = (const int*)d_in[2];
  const int* f0 = (const int*)d_in[3];
  const int* f1 = (const int*)d_in[4];
  const int* f2 = (const int*)d_in[5];
  const int* f3 = (const int*)d_in[6];
  const int* f4 = (const int*)d_in[7];
  const float* w0 = (const float*)d_in[8];
  const float* b0 = (const float*)d_in[9];
  const float* w1 = (const float*)d_in[10];
  const float* b1 = (const float*)d_in[11];
  const float* w2 = (const float*)d_in[12];
  const float* b2 = (const float*)d_in[13];
  const float* wh = (const float*)d_in[14];
  const float* bh = (const float*)d_in[15];
  float* outp = (float*)d_out;

  char* ws = (char*)d_ws;
  // ws layout (16B+ aligned): packed bf16 weights, small tables, activation bufs
  ushort_t* wP0 = (ushort_t*)(ws + 0);         // 512 x 4608 bf16 (4,718,592 B)
  ushort_t* wP1 = (ushort_t*)(ws + 4718592);   // 256 x 4608 bf16 (2,359,296 B)
  ushort_t* wP2 = (ushort_t*)(ws + 7077888);   // 256 x 2304 bf16 (1,179,648 B)
  float* whT    = (float*)(ws + 8257536);      // 3 x 2304 f32
  float* occ    = (float*)(ws + 8285184);      // 192 x 5 f32
  int* fid      = (int*)(ws + 8289024);        // 778 i32
  ushort_t* R0  = (ushort_t*)(ws + 8292352);   // wx, later h2   [64,V,256] bf16 25.5MB
  ushort_t* R1  = (ushort_t*)(ws + 33785856);  // h1, later h3   [64,V,512] bf16 51MB
  // total ws use: ~84.8 MB

  prep_misc<<<1, 256, 0, stream>>>(pred_occ, f0, f1, f2, f3, f4,
                                   in_sizes[3], in_sizes[4], in_sizes[5],
                                   in_sizes[6], in_sizes[7], wh, occ, fid, whT);
  pack_w<<<294912 / 256, 256, 0, stream>>>(w0, wP0, 512, 288, 294912);
  pack_w<<<147456 / 256, 256, 0, stream>>>(w1, wP1, 256, 288, 147456);
  pack_w<<<73728 / 256, 256, 0, stream>>>(w2, wP2, 256, 144, 73728);
  wx_kernel<<<6224, 256, 0, stream>>>(x, occ, fid, R0);

  dim3 g0(VN, 2), g1(VN, 1);
  // conv0: in [wx(bf16) | x_view0(f32)] (512ch) -> h1 (512ch bf16)
  spiral_gemm<512, true><<<g0, 256, 0, stream>>>(R0, x, wP0, b0, indices, R1, 512);
  // conv1: h1 (512ch) -> h2 (256ch)
  spiral_gemm<512, false><<<g1, 256, 0, stream>>>(R1, nullptr, wP1, b1, indices, R0, 256);
  // conv2: h2 (256ch) -> h3 (256ch)
  spiral_gemm<256, false><<<g1, 256, 0, stream>>>(R0, nullptr, wP2, b2, indices, R1, 256);
  // head: h3 -> out [64,V,3] f32
  head_kernel<<<VN, 256, 0, stream>>>(R1, whT, bh, indices, outp);
  (void)n_in; (void)out_size; (void)ws_size;
}

// Round 5
// 999.994 us; speedup vs baseline: 1.2049x; 1.0184x over previous
//
#include <hip/hip_runtime.h>

typedef unsigned short ushort_t;
typedef __attribute__((ext_vector_type(8))) __bf16 bf16x8;
typedef __attribute__((ext_vector_type(8))) unsigned short ushort8;
typedef __attribute__((ext_vector_type(4))) float floatx4;
typedef __attribute__((ext_vector_type(16))) float floatx16;

#define VN 778
#define KNB 9

__device__ __forceinline__ float bf2f(unsigned short s) {
  union { unsigned int u; float f; } x; x.u = ((unsigned int)s) << 16; return x.f;
}
__device__ __forceinline__ unsigned short f2bf(float f) {
  union { float f; unsigned int u; } x; x.f = f;
  unsigned int r = x.u + 0x7fffu + ((x.u >> 16) & 1u);
  return (unsigned short)(r >> 16);
}

// ---------------- prologue: occ probabilities, finger ids, wh transpose ----
__global__ void prep_misc(const float* __restrict__ pred_occ,
                          const int* f0, const int* f1, const int* f2,
                          const int* f3, const int* f4,
                          int n0, int n1, int n2, int n3, int n4,
                          const float* __restrict__ wh,
                          float* __restrict__ occ, int* __restrict__ fid,
                          float* __restrict__ whT) {
  int t = threadIdx.x;
  for (int i = t; i < 192 * 5; i += 256) {
    int r = i / 5, f = i % 5;
    float p0 = pred_occ[r * 10 + f];
    float p1 = pred_occ[r * 10 + 5 + f];
    occ[i] = 1.0f / (1.0f + __expf(p1 - p0));  // softmax over 2 classes, class 0
  }
  for (int i = t; i < VN; i += 256) fid[i] = -1;
  __syncthreads();
  const int* fp[5] = {f0, f1, f2, f3, f4};
  int fn[5] = {n0, n1, n2, n3, n4};
  for (int fi = 0; fi < 5; ++fi) {  // sequential: later fingers overwrite
    for (int i = t; i < fn[fi]; i += 256) fid[fp[fi][i]] = fi;
    __syncthreads();
  }
  for (int i = t; i < 3 * 2304; i += 256) {
    int o = i / 2304, k = i % 2304;
    whT[i] = wh[k * 3 + o];
  }
}

// ---------------- weighted view mix: wx[b,v,c] = sum_j softmax(w)_j x_j ----
// x is f32 [192,V,256]; output wx is bf16 [64,V,256].
__global__ void wx_kernel(const float* __restrict__ x, const float* __restrict__ occ,
                          const int* __restrict__ fid, ushort_t* __restrict__ wx) {
  int g = blockIdx.x * 256 + threadIdx.x;  // 8-ch chunk id over 64*778*32 (exact)
  int c8 = (g & 31) << 3;
  int bv = g >> 5;
  int b = bv / VN;
  int v = bv - b * VN;
  int f = fid[v];
  float w0 = 1.f, w1 = 1.f, w2 = 1.f;
  if (f >= 0) {
    w0 = occ[b * 5 + f];
    w1 = occ[(64 + b) * 5 + f];
    w2 = occ[(128 + b) * 5 + f];
  }
  float m = fmaxf(w0, fmaxf(w1, w2));
  float e0 = __expf(w0 - m), e1 = __expf(w1 - m), e2 = __expf(w2 - m);
  float inv = 1.0f / (e0 + e1 + e2);
  e0 *= inv; e1 *= inv; e2 *= inv;
  size_t base = (size_t)bv * 256 + c8;
  const size_t V1 = (size_t)64 * VN * 256, V2 = (size_t)128 * VN * 256;
  floatx4 x0a = *(const floatx4*)(x + base);
  floatx4 x0b = *(const floatx4*)(x + base + 4);
  floatx4 x1a = *(const floatx4*)(x + V1 + base);
  floatx4 x1b = *(const floatx4*)(x + V1 + base + 4);
  floatx4 x2a = *(const floatx4*)(x + V2 + base);
  floatx4 x2b = *(const floatx4*)(x + V2 + base + 4);
  ushort8 o;
#pragma unroll
  for (int e = 0; e < 4; ++e) {
    o[e]     = f2bf(e0 * x0a[e] + e1 * x1a[e] + e2 * x2a[e]);
    o[e + 4] = f2bf(e0 * x0b[e] + e1 * x1b[e] + e2 * x2b[e]);
  }
  *(ushort8*)(wx + base) = o;
}

// ---------------- pack W[k][n] (f32) into bf16 MFMA B-fragment order --------
// chunk = ((n/32)*(Ktot/16) + k/16)*64 + ((k%16)/8)*32 + (n%32); 8 bf16 (k-contig)
__global__ void pack_w(const float* __restrict__ w, ushort_t* __restrict__ wP,
                       int N, int ksn, int total) {
  int chunk = blockIdx.x * 256 + threadIdx.x;
  if (chunk >= total) return;
  int lane = chunk & 63;
  int rest = chunk >> 6;
  int ks = rest % ksn;
  int tn = rest / ksn;
  int n = (tn << 5) + (lane & 31);
  int kb = (ks << 4) + ((lane >> 5) << 3);
  ushort8 o;
#pragma unroll
  for (int j = 0; j < 8; ++j) o[j] = f2bf(w[(size_t)(kb + j) * N + n]);
  *(ushort8*)(wP + (size_t)chunk * 8) = o;
}

// ---------------- spiral gathered GEMM -------------------------------------
// block = TWO vertices, 512 threads (8 waves): wave = (vi, nq), tile 64m x 64n.
// B-stream amortized over 2 vertices (waves vi=0/1 with same nq read the same
// B addresses -> L1/L2). A staged per 128-channel phase (32 KB LDS), XOR
// swizzle on LDS-destination chunks. SPLIT: phases h=0,1 from bf16 act0 (wx),
// h=2,3 from f32 actF (x view 0) converted in-register.
template <int CIN, bool SPLIT>
__global__ __launch_bounds__(512, 4) void spiral_gemm(
    const ushort_t* __restrict__ act0, const float* __restrict__ actF,
    const ushort_t* __restrict__ wP, const float* __restrict__ bias,
    const int* __restrict__ idx, ushort_t* __restrict__ out, int NOUT) {
  constexpr int PHASES = CIN / 128;            // stage phases per neighbor
  __shared__ __align__(16) ushort_t Alds[2 * 64 * 128];  // 32 KB
  const int v0 = blockIdx.x * 2;
  const int n0 = blockIdx.y << 8;
  const int tid = threadIdx.x;
  const int lane = tid & 63;
  const int wv = tid >> 6;          // 0..7
  const int vi = wv >> 2;           // vertex within block
  const int nq = wv & 3;            // 64-n quarter within 256-n block range
  const int mlo = lane & 31;
  const int q = lane >> 5;
  const int xm = mlo & 7;
  floatx16 acc00{}, acc01{}, acc10{}, acc11{};
  const int KtotSteps = KNB * (CIN / 16);
  const int tn0 = (n0 >> 5) + (nq << 1);
  const ushort_t* bp0 = wP + (size_t)tn0 * KtotSteps * 512 + lane * 8;
  const ushort_t* bp1 = bp0 + (size_t)KtotSteps * 512;
  const int* iv0 = idx + v0 * KNB;
  const int* iv1 = idx + (v0 + 1) * KNB;
  const int a_off0 = vi * 64 * 128 + mlo * 128;         // elements
  const int a_off1 = vi * 64 * 128 + (mlo + 32) * 128;
  for (int nbr = 0; nbr < KNB; ++nbr) {
    const int nv0 = iv0[nbr], nv1 = iv1[nbr];
#pragma unroll
    for (int h = 0; h < PHASES; ++h) {
      __syncthreads();  // previous-phase readers done before restaging
#pragma unroll
      for (int it = 0; it < 4; ++it) {
        int L = it * 512 + tid;     // chunk id: [vv][row][ck], 2048 total
        int ck = L & 15;
        int row = (L >> 4) & 63;
        int vv = L >> 10;
        int nv = vv ? nv1 : nv0;
        int c = ck << 3;
        ushort8 val;
        if (SPLIT && h >= 2) {
          const float* src = actF + ((size_t)(row * VN + nv)) * 256 + (h - 2) * 128 + c;
          floatx4 fa = *(const floatx4*)src;
          floatx4 fb = *(const floatx4*)(src + 4);
#pragma unroll
          for (int e = 0; e < 4; ++e) { val[e] = f2bf(fa[e]); val[e + 4] = f2bf(fb[e]); }
        } else {
          const ushort_t* src = act0 + ((size_t)(row * VN + nv)) * (SPLIT ? 256 : CIN)
                                + h * 128 + c;
          val = *(const ushort8*)src;
        }
        int slot = ck ^ (row & 7);  // swizzle on LDS-destination side
        *(ushort8*)&Alds[(size_t)(vv * 64 * 128) + (size_t)(row * 16 + slot) * 8] = val;
      }
      __syncthreads();
#pragma unroll
      for (int ks = 0; ks < 8; ++ks) {
        int ck0 = ((ks << 1) + q) ^ xm;
        bf16x8 a0 = *(const bf16x8*)&Alds[a_off0 + ck0 * 8];
        bf16x8 a1 = *(const bf16x8*)&Alds[a_off1 + ck0 * 8];
        bf16x8 b0v = *(const bf16x8*)bp0; bp0 += 512;
        bf16x8 b1v = *(const bf16x8*)bp1; bp1 += 512;
        acc00 = __builtin_amdgcn_mfma_f32_32x32x16_bf16(a0, b0v, acc00, 0, 0, 0);
        acc10 = __builtin_amdgcn_mfma_f32_32x32x16_bf16(a1, b0v, acc10, 0, 0, 0);
        acc01 = __builtin_amdgcn_mfma_f32_32x32x16_bf16(a0, b1v, acc01, 0, 0, 0);
        acc11 = __builtin_amdgcn_mfma_f32_32x32x16_bf16(a1, b1v, acc11, 0, 0, 0);
      }
    }
  }
  // epilogue: C/D layout col=lane&31, row=(reg&3)+8*(reg>>2)+4*(lane>>5)
  const int v = v0 + vi;
  const int na = n0 + (nq << 6) + mlo;
  const int nb = na + 32;
  const float ba = bias[na];
  const float bb = bias[nb];
#pragma unroll
  for (int r = 0; r < 16; ++r) {
    int m = (r & 3) + ((r >> 2) << 3) + (q << 2);
    size_t o0 = ((size_t)(m * VN + v)) * NOUT;
    size_t o1 = ((size_t)((m + 32) * VN + v)) * NOUT;
    float v00 = acc00[r] + ba; v00 = v00 > 0.f ? v00 : 0.f;
    float v01 = acc01[r] + bb; v01 = v01 > 0.f ? v01 : 0.f;
    float v10 = acc10[r] + ba; v10 = v10 > 0.f ? v10 : 0.f;
    float v11 = acc11[r] + bb; v11 = v11 > 0.f ? v11 : 0.f;
    out[o0 + na] = f2bf(v00);
    out[o0 + nb] = f2bf(v01);
    out[o1 + na] = f2bf(v10);
    out[o1 + nb] = f2bf(v11);
  }
}

// ---------------- head: gathered [64 x 2304] @ [2304 x 3], f32 out ---------
__global__ void head_kernel(const ushort_t* __restrict__ act, const float* __restrict__ whT,
                            const float* __restrict__ bh, const int* __restrict__ idx,
                            float* __restrict__ out) {
  __shared__ __align__(16) ushort_t Alds[64 * 256];
  const int v = blockIdx.x;
  const int tid = threadIdx.x;
  float a0 = 0.f, a1 = 0.f, a2 = 0.f;
  const int b = tid;  // valid when tid < 64
  const int xm = b & 7;
  for (int nbr = 0; nbr < KNB; ++nbr) {
    const int nv = idx[v * KNB + nbr];
    __syncthreads();
#pragma unroll
    for (int it = 0; it < 8; ++it) {
      int L = it * 256 + tid;
      int bb = L >> 5;
      int jj = L & 31;
      ushort8 val = *(const ushort8*)(act + ((size_t)(bb * VN + nv)) * 256 + (jj << 3));
      int slot = jj ^ (bb & 7);
      *(ushort8*)&Alds[(size_t)(bb * 32 + slot) * 8] = val;
    }
    __syncthreads();
    if (tid < 64) {
      const float* wp = whT + nbr * 256;
#pragma unroll 4
      for (int j = 0; j < 32; ++j) {
        int jj = j ^ xm;
        ushort8 a8 = *(const ushort8*)&Alds[(b * 32 + jj) * 8];
#pragma unroll
        for (int e = 0; e < 8; ++e) {
          float av = bf2f(a8[e]);
          int k = (j << 3) + e;
          a0 += av * wp[k];
          a1 += av * wp[2304 + k];
          a2 += av * wp[4608 + k];
        }
      }
    }
  }
  if (tid < 64) {
    size_t o = ((size_t)(b * VN + v)) * 3;
    out[o + 0] = a0 + bh[0];
    out[o + 1] = a1 + bh[1];
    out[o + 2] = a2 + bh[2];
  }
}

extern "C" void kernel_launch(void* const* d_in, const int* in_sizes, int n_in,
                              void* d_out, int out_size, void* d_ws, size_t ws_size,
                              hipStream_t stream) {
  const float* x        = (const float*)d_in[0];
  const float* pred_occ = (const float*)d_in[1];
  const int* indices    = (const int*)d_in[2];
  const int* f0 = (const int*)d_in[3];
  const int* f1 = (const int*)d_in[4];
  const int* f2 = (const int*)d_in[5];
  const int* f3 = (const int*)d_in[6];
  const int* f4 = (const int*)d_in[7];
  const float* w0 = (const float*)d_in[8];
  const float* b0 = (const float*)d_in[9];
  const float* w1 = (const float*)d_in[10];
  const float* b1 = (const float*)d_in[11];
  const float* w2 = (const float*)d_in[12];
  const float* b2 = (const float*)d_in[13];
  const float* wh = (const float*)d_in[14];
  const float* bh = (const float*)d_in[15];
  float* outp = (float*)d_out;

  char* ws = (char*)d_ws;
  // ws layout (16B+ aligned): packed bf16 weights, small tables, activation bufs
  ushort_t* wP0 = (ushort_t*)(ws + 0);         // 512 x 4608 bf16 (4,718,592 B)
  ushort_t* wP1 = (ushort_t*)(ws + 4718592);   // 256 x 4608 bf16 (2,359,296 B)
  ushort_t* wP2 = (ushort_t*)(ws + 7077888);   // 256 x 2304 bf16 (1,179,648 B)
  float* whT    = (float*)(ws + 8257536);      // 3 x 2304 f32
  float* occ    = (float*)(ws + 8285184);      // 192 x 5 f32
  int* fid      = (int*)(ws + 8289024);        // 778 i32
  ushort_t* R0  = (ushort_t*)(ws + 8292352);   // wx, later h2   [64,V,256] bf16 25.5MB
  ushort_t* R1  = (ushort_t*)(ws + 33785856);  // h1, later h3   [64,V,512] bf16 51MB
  // total ws use: ~84.8 MB

  prep_misc<<<1, 256, 0, stream>>>(pred_occ, f0, f1, f2, f3, f4,
                                   in_sizes[3], in_sizes[4], in_sizes[5],
                                   in_sizes[6], in_sizes[7], wh, occ, fid, whT);
  pack_w<<<294912 / 256, 256, 0, stream>>>(w0, wP0, 512, 288, 294912);
  pack_w<<<147456 / 256, 256, 0, stream>>>(w1, wP1, 256, 288, 147456);
  pack_w<<<73728 / 256, 256, 0, stream>>>(w2, wP2, 256, 144, 73728);
  wx_kernel<<<6224, 256, 0, stream>>>(x, occ, fid, R0);

  dim3 g0(VN / 2, 2), g1(VN / 2, 1);   // 778 even -> no vertex guard needed
  // conv0: in [wx(bf16) | x_view0(f32)] (512ch) -> h1 (512ch bf16)
  spiral_gemm<512, true><<<g0, 512, 0, stream>>>(R0, x, wP0, b0, indices, R1, 512);
  // conv1: h1 (512ch) -> h2 (256ch)
  spiral_gemm<512, false><<<g1, 512, 0, stream>>>(R1, nullptr, wP1, b1, indices, R0, 256);
  // conv2: h2 (256ch) -> h3 (256ch)
  spiral_gemm<256, false><<<g1, 512, 0, stream>>>(R0, nullptr, wP2, b2, indices, R1, 256);
  // head: h3 -> out [64,V,3] f32
  head_kernel<<<VN, 256, 0, stream>>>(R1, whT, bh, indices, outp);
  (void)n_in; (void)out_size; (void)ws_size;
}

// Round 6
// 852.720 us; speedup vs baseline: 1.4130x; 1.1727x over previous
//
#include <hip/hip_runtime.h>

typedef unsigned short ushort_t;
typedef __attribute__((ext_vector_type(8))) __bf16 bf16x8;
typedef __attribute__((ext_vector_type(8))) unsigned short ushort8;
typedef __attribute__((ext_vector_type(4))) float floatx4;
typedef __attribute__((ext_vector_type(16))) float floatx16;

#define VN 778
#define KNB 9

__device__ __forceinline__ float bf2f(unsigned short s) {
  union { unsigned int u; float f; } x; x.u = ((unsigned int)s) << 16; return x.f;
}
__device__ __forceinline__ unsigned short f2bf(float f) {
  union { float f; unsigned int u; } x; x.f = f;
  unsigned int r = x.u + 0x7fffu + ((x.u >> 16) & 1u);
  return (unsigned short)(r >> 16);
}

// async global -> LDS, 16B per lane; LDS dest = wave-uniform base + lane*16.
__device__ __forceinline__ void load_lds16(const void* g, void* l) {
  __builtin_amdgcn_global_load_lds(
      (const __attribute__((address_space(1))) unsigned int*)g,
      (__attribute__((address_space(3))) unsigned int*)l, 16, 0, 0);
}

// ---------------- prologue: occ probabilities, finger ids, wh transpose ----
__global__ void prep_misc(const float* __restrict__ pred_occ,
                          const int* f0, const int* f1, const int* f2,
                          const int* f3, const int* f4,
                          int n0, int n1, int n2, int n3, int n4,
                          const float* __restrict__ wh,
                          float* __restrict__ occ, int* __restrict__ fid,
                          float* __restrict__ whT) {
  int t = threadIdx.x;
  for (int i = t; i < 192 * 5; i += 256) {
    int r = i / 5, f = i % 5;
    float p0 = pred_occ[r * 10 + f];
    float p1 = pred_occ[r * 10 + 5 + f];
    occ[i] = 1.0f / (1.0f + __expf(p1 - p0));  // softmax over 2 classes, class 0
  }
  for (int i = t; i < VN; i += 256) fid[i] = -1;
  __syncthreads();
  const int* fp[5] = {f0, f1, f2, f3, f4};
  int fn[5] = {n0, n1, n2, n3, n4};
  for (int fi = 0; fi < 5; ++fi) {  // sequential: later fingers overwrite
    for (int i = t; i < fn[fi]; i += 256) fid[fp[fi][i]] = fi;
    __syncthreads();
  }
  for (int i = t; i < 3 * 2304; i += 256) {
    int o = i / 2304, k = i % 2304;
    whT[i] = wh[k * 3 + o];
  }
}

// ---------------- weighted view mix: wx[b,v,c] (bf16 out) ------------------
__global__ void wx_kernel(const float* __restrict__ x, const float* __restrict__ occ,
                          const int* __restrict__ fid, ushort_t* __restrict__ wx) {
  int g = blockIdx.x * 256 + threadIdx.x;  // 8-ch chunk id over 64*778*32 (exact)
  int c8 = (g & 31) << 3;
  int bv = g >> 5;
  int b = bv / VN;
  int v = bv - b * VN;
  int f = fid[v];
  float w0 = 1.f, w1 = 1.f, w2 = 1.f;
  if (f >= 0) {
    w0 = occ[b * 5 + f];
    w1 = occ[(64 + b) * 5 + f];
    w2 = occ[(128 + b) * 5 + f];
  }
  float m = fmaxf(w0, fmaxf(w1, w2));
  float e0 = __expf(w0 - m), e1 = __expf(w1 - m), e2 = __expf(w2 - m);
  float inv = 1.0f / (e0 + e1 + e2);
  e0 *= inv; e1 *= inv; e2 *= inv;
  size_t base = (size_t)bv * 256 + c8;
  const size_t V1 = (size_t)64 * VN * 256, V2 = (size_t)128 * VN * 256;
  floatx4 x0a = *(const floatx4*)(x + base);
  floatx4 x0b = *(const floatx4*)(x + base + 4);
  floatx4 x1a = *(const floatx4*)(x + V1 + base);
  floatx4 x1b = *(const floatx4*)(x + V1 + base + 4);
  floatx4 x2a = *(const floatx4*)(x + V2 + base);
  floatx4 x2b = *(const floatx4*)(x + V2 + base + 4);
  ushort8 o;
#pragma unroll
  for (int e = 0; e < 4; ++e) {
    o[e]     = f2bf(e0 * x0a[e] + e1 * x1a[e] + e2 * x2a[e]);
    o[e + 4] = f2bf(e0 * x0b[e] + e1 * x1b[e] + e2 * x2b[e]);
  }
  *(ushort8*)(wx + base) = o;
}

// ---------------- x view-0 f32 -> bf16 copy --------------------------------
__global__ void xcvt_kernel(const float* __restrict__ x, ushort_t* __restrict__ xb) {
  int g = blockIdx.x * 256 + threadIdx.x;
  size_t base = (size_t)g * 8;
  floatx4 fa = *(const floatx4*)(x + base);
  floatx4 fb = *(const floatx4*)(x + base + 4);
  ushort8 o;
#pragma unroll
  for (int e = 0; e < 4; ++e) { o[e] = f2bf(fa[e]); o[e + 4] = f2bf(fb[e]); }
  *(ushort8*)(xb + base) = o;
}

// ---------------- pack W[k][n] (f32) into bf16 MFMA B-fragment order --------
// chunk = ((n/32)*(Ktot/16) + k/16)*64 + ((k%16)/8)*32 + (n%32); 8 bf16 (k-contig)
__global__ void pack_w(const float* __restrict__ w, ushort_t* __restrict__ wP,
                       int N, int ksn, int total) {
  int chunk = blockIdx.x * 256 + threadIdx.x;
  if (chunk >= total) return;
  int lane = chunk & 63;
  int rest = chunk >> 6;
  int ks = rest % ksn;
  int tn = rest / ksn;
  int n = (tn << 5) + (lane & 31);
  int kb = (ks << 4) + ((lane >> 5) << 3);
  ushort8 o;
#pragma unroll
  for (int j = 0; j < 8; ++j) o[j] = f2bf(w[(size_t)(kb + j) * N + n]);
  *(ushort8*)(wP + (size_t)chunk * 8) = o;
}

// ---------------- spiral gathered GEMM -------------------------------------
// block = 2 vertices, 512 threads (8 waves); wave tile = 128m(2v x 64b) x 32n.
// 1 B-load per 4 MFMA. A double-buffered in 128-ch phases (2 x 32 KB LDS),
// staged by global_load_lds DMA with swizzle on the SOURCE side (LDS dest is
// lane-linear), prefetched one phase ahead; ONE barrier per phase.
// MODE 0: single bf16 act (rowstride CIN). MODE 1: wx bf16 + x f32 (f32
// phases staged synchronously). MODE 2: wx bf16 + pre-converted bf16 xb.
template <int CIN, int MODE>
__global__ __launch_bounds__(512, 4) void spiral_gemm(
    const ushort_t* __restrict__ act0, const float* __restrict__ actF,
    const ushort_t* __restrict__ actB, const ushort_t* __restrict__ wP,
    const float* __restrict__ bias, const int* __restrict__ idx,
    ushort_t* __restrict__ out, int NOUT) {
  constexpr int H = CIN / 128;       // 128-ch phases per neighbor
  constexpr int P = KNB * H;
  __shared__ __align__(16) ushort_t Alds[2][2048 * 8];   // 2 x 32 KB
  const int v0 = blockIdx.x * 2;
  const int n0 = blockIdx.y << 8;
  const int tid = threadIdx.x;
  const int lane = tid & 63;
  const int wv = tid >> 6;           // n-strip (0..7)
  const int mlo = lane & 31;
  const int q = lane >> 5;
  const int xm = mlo & 7;
  floatx16 acc0{}, acc1{}, acc2{}, acc3{};
  const int KtotSteps = KNB * (CIN / 16);
  const int tn0 = (n0 >> 5) + wv;
  const ushort_t* bp = wP + (size_t)tn0 * KtotSteps * 512 + lane * 8;
  const int* iv0 = idx + v0 * KNB;
  const int* iv1 = iv0 + KNB;
  // A-frag element offsets (ck part added per ks); LDS elem = vv*8192+row*128+ck*8
  const int aoff0 = mlo * 128;
  const int aoff1 = (mlo + 32) * 128;
  const int aoff2 = 8192 + mlo * 128;
  const int aoff3 = 8192 + (mlo + 32) * 128;

  auto dma_stage = [&](int p, ushort_t* buf) {  // bf16 phases only
    const int nbr = p / H, h = p - nbr * H;
    const int nva = iv0[nbr], nvb = iv1[nbr];
#pragma unroll
    for (int it = 0; it < 4; ++it) {
      const int slotb = ((wv << 2) + it) << 6;   // wave-uniform slot base
      const int s = slotb + lane;
      const int vv = s >> 10;
      const int row = (s >> 4) & 63;
      const int ck = (s & 15) ^ (row & 7);       // swizzle on source side
      const int nv = vv ? nvb : nva;
      const ushort_t* src;
      if (MODE == 0) {
        src = act0 + ((size_t)(row * VN + nv)) * CIN + h * 128 + ck * 8;
      } else {
        const ushort_t* basep = (MODE == 1 || h < 2) ? act0 : actB;
        src = basep + ((size_t)(row * VN + nv)) * 256 + (h & 1) * 128 + ck * 8;
      }
      load_lds16(src, buf + (size_t)slotb * 8);
    }
  };
  auto f32_stage = [&](int p, ushort_t* buf) {  // MODE 1, h in {2,3}
    const int nbr = p / H, h = p - nbr * H;
    const int nva = iv0[nbr], nvb = iv1[nbr];
#pragma unroll
    for (int j = 0; j < 4; ++j) {
      const int s = (j << 9) + tid;
      const int vv = s >> 10;
      const int row = (s >> 4) & 63;
      const int ck = (s & 15) ^ (row & 7);
      const int nv = vv ? nvb : nva;
      const float* src = actF + ((size_t)(row * VN + nv)) * 256 + (h - 2) * 128 + ck * 8;
      floatx4 fa = *(const floatx4*)src;
      floatx4 fb = *(const floatx4*)(src + 4);
      ushort8 o;
#pragma unroll
      for (int e = 0; e < 4; ++e) { o[e] = f2bf(fa[e]); o[e + 4] = f2bf(fb[e]); }
      *(ushort8*)(buf + (size_t)s * 8) = o;
    }
  };

  dma_stage(0, Alds[0]);   // phase 0 is always bf16 (h=0)
  __syncthreads();
#pragma unroll 2
  for (int p = 0; p < P; ++p) {
    ushort_t* cur = Alds[p & 1];
    ushort_t* nxt = Alds[(p + 1) & 1];
    const bool have_next = (p + 1 < P);
    const bool next_f32 = (MODE == 1) && (((p + 1) & (H - 1)) >= 2);
    if (have_next && !next_f32) dma_stage(p + 1, nxt);
#pragma unroll
    for (int ks = 0; ks < 8; ++ks) {
      const int cko = ((((ks << 1) + q) ^ xm) << 3);
      bf16x8 a0 = *(const bf16x8*)(cur + aoff0 + cko);
      bf16x8 a1 = *(const bf16x8*)(cur + aoff1 + cko);
      bf16x8 a2 = *(const bf16x8*)(cur + aoff2 + cko);
      bf16x8 a3 = *(const bf16x8*)(cur + aoff3 + cko);
      bf16x8 bv = *(const bf16x8*)bp; bp += 512;
      acc0 = __builtin_amdgcn_mfma_f32_32x32x16_bf16(a0, bv, acc0, 0, 0, 0);
      acc1 = __builtin_amdgcn_mfma_f32_32x32x16_bf16(a1, bv, acc1, 0, 0, 0);
      acc2 = __builtin_amdgcn_mfma_f32_32x32x16_bf16(a2, bv, acc2, 0, 0, 0);
      acc3 = __builtin_amdgcn_mfma_f32_32x32x16_bf16(a3, bv, acc3, 0, 0, 0);
    }
    __syncthreads();   // drains DMA vmcnt; all waves done reading cur
    if (have_next && next_f32) { f32_stage(p + 1, nxt); __syncthreads(); }
  }
  // epilogue: C/D layout col=lane&31 (=n), row=(reg&3)+8*(reg>>2)+4*(lane>>5)
  const int n = n0 + (wv << 5) + mlo;
  const float bn = bias[n];
#pragma unroll
  for (int t = 0; t < 4; ++t) {
    const floatx16 av = (t == 0) ? acc0 : (t == 1) ? acc1 : (t == 2) ? acc2 : acc3;
    const int vcur = v0 + (t >> 1);
    const int bbase = (t & 1) << 5;
#pragma unroll
    for (int r = 0; r < 16; ++r) {
      const int m = (r & 3) + ((r >> 2) << 3) + (q << 2);
      float val = av[r] + bn; val = val > 0.f ? val : 0.f;
      out[((size_t)((bbase + m) * VN + vcur)) * NOUT + n] = f2bf(val);
    }
  }
}

// ---------------- head: gathered [64 x 2304] @ [2304 x 3], f32 out ---------
__global__ void head_kernel(const ushort_t* __restrict__ act, const float* __restrict__ whT,
                            const float* __restrict__ bh, const int* __restrict__ idx,
                            float* __restrict__ out) {
  __shared__ __align__(16) ushort_t Alds[64 * 256];
  const int v = blockIdx.x;
  const int tid = threadIdx.x;
  float a0 = 0.f, a1 = 0.f, a2 = 0.f;
  const int b = tid;  // valid when tid < 64
  const int xm = b & 7;
  for (int nbr = 0; nbr < KNB; ++nbr) {
    const int nv = idx[v * KNB + nbr];
    __syncthreads();
#pragma unroll
    for (int it = 0; it < 8; ++it) {
      int L = it * 256 + tid;
      int bb = L >> 5;
      int jj = L & 31;
      ushort8 val = *(const ushort8*)(act + ((size_t)(bb * VN + nv)) * 256 + (jj << 3));
      int slot = jj ^ (bb & 7);
      *(ushort8*)&Alds[(size_t)(bb * 32 + slot) * 8] = val;
    }
    __syncthreads();
    if (tid < 64) {
      const float* wp = whT + nbr * 256;
#pragma unroll 4
      for (int j = 0; j < 32; ++j) {
        int jj = j ^ xm;
        ushort8 a8 = *(const ushort8*)&Alds[(b * 32 + jj) * 8];
#pragma unroll
        for (int e = 0; e < 8; ++e) {
          float av = bf2f(a8[e]);
          int k = (j << 3) + e;
          a0 += av * wp[k];
          a1 += av * wp[2304 + k];
          a2 += av * wp[4608 + k];
        }
      }
    }
  }
  if (tid < 64) {
    size_t o = ((size_t)(b * VN + v)) * 3;
    out[o + 0] = a0 + bh[0];
    out[o + 1] = a1 + bh[1];
    out[o + 2] = a2 + bh[2];
  }
}

extern "C" void kernel_launch(void* const* d_in, const int* in_sizes, int n_in,
                              void* d_out, int out_size, void* d_ws, size_t ws_size,
                              hipStream_t stream) {
  const float* x        = (const float*)d_in[0];
  const float* pred_occ = (const float*)d_in[1];
  const int* indices    = (const int*)d_in[2];
  const int* f0 = (const int*)d_in[3];
  const int* f1 = (const int*)d_in[4];
  const int* f2 = (const int*)d_in[5];
  const int* f3 = (const int*)d_in[6];
  const int* f4 = (const int*)d_in[7];
  const float* w0 = (const float*)d_in[8];
  const float* b0 = (const float*)d_in[9];
  const float* w1 = (const float*)d_in[10];
  const float* b1 = (const float*)d_in[11];
  const float* w2 = (const float*)d_in[12];
  const float* b2 = (const float*)d_in[13];
  const float* wh = (const float*)d_in[14];
  const float* bh = (const float*)d_in[15];
  float* outp = (float*)d_out;

  char* ws = (char*)d_ws;
  ushort_t* wP0 = (ushort_t*)(ws + 0);         // 512 x 4608 bf16 (4,718,592 B)
  ushort_t* wP1 = (ushort_t*)(ws + 4718592);   // 256 x 4608 bf16 (2,359,296 B)
  ushort_t* wP2 = (ushort_t*)(ws + 7077888);   // 256 x 2304 bf16 (1,179,648 B)
  float* whT    = (float*)(ws + 8257536);      // 3 x 2304 f32
  float* occ    = (float*)(ws + 8285184);      // 192 x 5 f32
  int* fid      = (int*)(ws + 8289024);        // 778 i32
  ushort_t* R0  = (ushort_t*)(ws + 8292352);   // wx, later h2   [64,V,256] 25.5MB
  ushort_t* R1  = (ushort_t*)(ws + 33785856);  // h1, later h3   [64,V,512] 51MB
  ushort_t* XB  = (ushort_t*)(ws + 84772864);  // optional bf16 x view0, 25.5MB
  const bool useXB = (ws_size >= 110266368ull);

  prep_misc<<<1, 256, 0, stream>>>(pred_occ, f0, f1, f2, f3, f4,
                                   in_sizes[3], in_sizes[4], in_sizes[5],
                                   in_sizes[6], in_sizes[7], wh, occ, fid, whT);
  pack_w<<<294912 / 256, 256, 0, stream>>>(w0, wP0, 512, 288, 294912);
  pack_w<<<147456 / 256, 256, 0, stream>>>(w1, wP1, 256, 288, 147456);
  pack_w<<<73728 / 256, 256, 0, stream>>>(w2, wP2, 256, 144, 73728);
  if (useXB) xcvt_kernel<<<6224, 256, 0, stream>>>(x, XB);
  wx_kernel<<<6224, 256, 0, stream>>>(x, occ, fid, R0);

  // conv0: [wx | x_view0] (512ch) -> h1 (512ch bf16)
  if (useXB)
    spiral_gemm<512, 2><<<dim3(389, 2), 512, 0, stream>>>(R0, nullptr, XB, wP0, b0,
                                                          indices, R1, 512);
  else
    spiral_gemm<512, 1><<<dim3(389, 2), 512, 0, stream>>>(R0, x, nullptr, wP0, b0,
                                                          indices, R1, 512);
  // conv1: h1 (512ch) -> h2 (256ch)
  spiral_gemm<512, 0><<<dim3(389, 1), 512, 0, stream>>>(R1, nullptr, nullptr, wP1, b1,
                                                        indices, R0, 256);
  // conv2: h2 (256ch) -> h3 (256ch)
  spiral_gemm<256, 0><<<dim3(389, 1), 512, 0, stream>>>(R0, nullptr, nullptr, wP2, b2,
                                                        indices, R1, 256);
  // head: h3 -> out [64,V,3] f32
  head_kernel<<<VN, 256, 0, stream>>>(R1, whT, bh, indices, outp);
  (void)n_in; (void)out_size;
}